// Round 5
// baseline (383.739 us; speedup 1.0000x reference)
//
#include <hip/hip_runtime.h>
#include <math.h>

#define NB 32
#define NP 24656
#define NO 16
#define NC 81
#define ND 85   // 4 + NC
#define THRESH_F 0.5f
#define NEGPOS_I 3
#define VAR0_F 0.1f
#define VAR1_F 0.2f
#define NEG_HUGE -1e30f

#define BPCNT (NB * NP)
#define MBLK 97          // k_match blocks per batch row = ceil(NP/256)

typedef unsigned long long u64;

// ---------------------------------------------------------------- init
__global__ void k_init(int* __restrict__ npos, float* __restrict__ accB) {
    int t = threadIdx.x;
    if (t < NB) npos[t] = 0;
    if (t < 2 * NB) accB[t] = 0.f;
}

// ---------------------------------------------------------------- match
// per (b,p): best truth over O (first-max tie) -> bt2.
// per (b,o): block-level argmax candidate (key = iou_bits<<32 | ~p) written
// to mcand[(b*NO+o)*MBLK + bx]. NO global atomics.
__global__ __launch_bounds__(256) void k_match(
    const float* __restrict__ tboxes, const float* __restrict__ priors,
    float2* __restrict__ bt2, u64* __restrict__ mcand) {
    const int b = blockIdx.y;
    const int bx = blockIdx.x;
    const int tid = threadIdx.x;
    const int p = bx * 256 + tid;
    const int lane = tid & 63;
    const int wv = tid >> 6;
    __shared__ float tb[NO * 4];
    __shared__ u64 wkey[4][NO];
    if (tid < NO * 4) tb[tid] = tboxes[b * NO * 4 + tid];
    __syncthreads();

    const bool valid = (p < NP);
    float4 pr = make_float4(0.f, 0.f, 1.f, 1.f);
    if (valid) pr = *(const float4*)(priors + (size_t)p * 4);
    const float pl = pr.x - pr.z * 0.5f, pt = pr.y - pr.w * 0.5f;
    const float prr = pr.x + pr.z * 0.5f, pb = pr.y + pr.w * 0.5f;
    const float parea = (prr - pl) * (pb - pt);

    float bestv = -1.f;
    int besti = 0;
    for (int o = 0; o < NO; ++o) {
        const float al = tb[o * 4 + 0], at = tb[o * 4 + 1];
        const float ar = tb[o * 4 + 2], ab = tb[o * 4 + 3];
        float iw = fminf(ar, prr) - fmaxf(al, pl); iw = fmaxf(iw, 0.f);
        float ih = fminf(ab, pb) - fmaxf(at, pt); ih = fmaxf(ih, 0.f);
        const float inter = iw * ih;
        const float aarea = (ar - al) * (ab - at);
        float iou = inter / (aarea + parea - inter);
        if (!valid) iou = -1.f;
        if (iou > bestv) { bestv = iou; besti = o; }

        float m = iou;
        for (int d = 1; d < 64; d <<= 1) m = fmaxf(m, __shfl_xor(m, d, 64));
        u64 key = 0ull;
        if (m >= 0.f) {
            unsigned long long msk = __ballot(iou == m);
            int lam = __ffsll(msk) - 1;
            int pw = bx * 256 + (tid & ~63) + lam;
            key = ((u64)__float_as_uint(m) << 32) |
                  (u64)(0xFFFFFFFFu - (unsigned)pw);
        }
        if (lane == 0) wkey[wv][o] = key;
    }
    if (valid)
        bt2[(size_t)b * NP + p] = make_float2(bestv, __int_as_float(besti));
    __syncthreads();
    if (tid < NO) {
        u64 k0 = wkey[0][tid];
        k0 = (wkey[1][tid] > k0) ? wkey[1][tid] : k0;
        k0 = (wkey[2][tid] > k0) ? wkey[2][tid] : k0;
        k0 = (wkey[3][tid] > k0) ? wkey[3][tid] : k0;
        mcand[((size_t)(b * NO + tid)) * MBLK + bx] = k0;
    }
}

// ---------------------------------------------------------------- scatter
// 512 threads = (b,o) pairs: reduce MBLK candidates; then per-b sequential
// o-ascending scatter (last-o-wins semantics preserved).
__global__ __launch_bounds__(512) void k_scatter(const u64* __restrict__ mcand,
                                                 float2* __restrict__ bt2) {
    __shared__ int pbest[NB * NO];
    const int t = threadIdx.x;
    const u64* c = mcand + (size_t)t * MBLK;
    u64 best = 0ull;
    for (int i = 0; i < MBLK; ++i) {
        u64 v = c[i];
        best = (v > best) ? v : best;
    }
    pbest[t] = (int)(0xFFFFFFFFu - (unsigned)(best & 0xFFFFFFFFull));
    __syncthreads();
    if (t < NB) {
        for (int o = 0; o < NO; ++o) {
            int p = pbest[t * NO + o];
            bt2[(size_t)t * NP + p] = make_float2(2.0f, __int_as_float(o));
        }
    }
}

// ---------------------------------------------------------------- main fused
// 256 threads / 64 rows: coalesced float4 stage into LDS, then 4 lanes per
// row (quad) with ~21 register-resident logits each; quad-reduce via 2
// shfl_xor. Row stride 85 dwords (odd) -> <=2-way LDS bank aliasing (free).
__global__ __launch_bounds__(256) void k_main(
    const float* __restrict__ pred, const float* __restrict__ tboxes,
    const int* __restrict__ tlabels, const float* __restrict__ priors,
    const float2* __restrict__ bt2,
    float* __restrict__ lr, int* __restrict__ npos, float* __restrict__ accB) {
    __shared__ float rows[64 * ND];  // 21760 B

    const int b = blockIdx.y;
    const int r0 = blockIdx.x * 64;
    const int tid = threadIdx.x;
    const int nrows = min(64, NP - r0);
    const size_t bbase = (size_t)b * NP;

    // phase A: coalesced stage (base 16B-aligned: (b*NP + r0)*85 % 4 == 0)
    {
        const float4* src = (const float4*)(pred + (bbase + r0) * ND);
        float4* dst = (float4*)rows;
        const int nF4 = nrows * ND / 4;  // 1360 or 340
        for (int i = tid; i < nF4; i += 256) dst[i] = src[i];
    }
    __syncthreads();

    const int w = tid >> 2, q = tid & 3;
    const bool active = (w < nrows);
    const int cstart = (q == 0) ? 0 : (21 + 20 * (q - 1));
    const int ccnt = (q == 0) ? 21 : 20;
    const float* rp = rows + w * ND;

    // register-load this quad's class logits (clamped idx, masked value)
    float vals[21];
#pragma unroll
    for (int j = 0; j < 21; ++j) {
        const int jj = (j < ccnt) ? j : (ccnt - 1);
        const float x = rp[4 + cstart + jj];
        vals[j] = (j < ccnt) ? x : NEG_HUGE;
    }
    float mx = vals[0];
#pragma unroll
    for (int j = 1; j < 21; ++j) mx = fmaxf(mx, vals[j]);
    mx = fmaxf(mx, __shfl_xor(mx, 1, 64));
    mx = fmaxf(mx, __shfl_xor(mx, 2, 64));
    float s = 0.f;
#pragma unroll
    for (int j = 0; j < 21; ++j) s += __expf(vals[j] - mx);
    s += __shfl_xor(s, 1, 64);
    s += __shfl_xor(s, 2, 64);
    const float lse = mx + __logf(s);

    float my_ll = 0.f, my_ce = 0.f;
    int my_np = 0;
    if (q == 0 && active) {
        const int p = r0 + w;
        const float2 bt = bt2[bbase + p];
        const bool pos = (bt.x >= THRESH_F);
        const int o = __float_as_int(bt.y);
        const float bg = rp[4];
        lr[bbase + p] = pos ? 0.f : (lse - bg);
        if (pos) {
            my_np = 1;
            const int lbl = tlabels[b * NO + o] + 1;
            my_ce = lse - rp[4 + lbl];
            const float4 pr = *((const float4*)priors + p);
            const float tx0 = tboxes[(b * NO + o) * 4 + 0];
            const float ty0 = tboxes[(b * NO + o) * 4 + 1];
            const float tx1 = tboxes[(b * NO + o) * 4 + 2];
            const float ty1 = tboxes[(b * NO + o) * 4 + 3];
            const float g0 = ((tx0 + tx1) * 0.5f - pr.x) / (VAR0_F * pr.z);
            const float g1 = ((ty0 + ty1) * 0.5f - pr.y) / (VAR0_F * pr.w);
            const float g2 = __logf((tx1 - tx0) / pr.z) / VAR1_F;
            const float g3 = __logf((ty1 - ty0) / pr.w) / VAR1_F;
            float dd, ad;
            dd = rp[0] - g0; ad = fabsf(dd); my_ll += (ad < 1.f) ? 0.5f * dd * dd : (ad - 0.5f);
            dd = rp[1] - g1; ad = fabsf(dd); my_ll += (ad < 1.f) ? 0.5f * dd * dd : (ad - 0.5f);
            dd = rp[2] - g2; ad = fabsf(dd); my_ll += (ad < 1.f) ? 0.5f * dd * dd : (ad - 0.5f);
            dd = rp[3] - g3; ad = fabsf(dd); my_ll += (ad < 1.f) ? 0.5f * dd * dd : (ad - 0.5f);
        }
    }
    for (int d2 = 1; d2 < 64; d2 <<= 1) {
        my_ll += __shfl_xor(my_ll, d2, 64);
        my_ce += __shfl_xor(my_ce, d2, 64);
        my_np += __shfl_xor(my_np, d2, 64);
    }
    if ((tid & 63) == 0) {
        if (my_ll != 0.f) atomicAdd(&accB[b * 2 + 0], my_ll);
        if (my_ce != 0.f) atomicAdd(&accB[b * 2 + 1], my_ce);
        if (my_np) atomicAdd(&npos[b], my_np);
    }
}

// ---------------------------------------------------------------- select
__global__ __launch_bounds__(1024) void k_select(
    const float* __restrict__ lrk, const int* __restrict__ npos,
    float* __restrict__ accB) {
    const int b = blockIdx.x;
    const float* row = lrk + (size_t)b * NP;
    const int tid = threadIdx.x;
    const int lane = tid & 63;
    const int wid = tid >> 6;

    __shared__ unsigned whist[16][256];
    __shared__ unsigned chist[256];
    __shared__ int sh_bucket, sh_knew;
    __shared__ float wsum[16];
    __shared__ int wcnt[16];

    const int K0 = min(npos[b] * NEGPOS_I, NP);
    int k = K0;
    unsigned prefix = 0;

    for (int shift = 24; shift >= 0; shift -= 8) {
        for (int j = lane; j < 256; j += 64) whist[wid][j] = 0;
        __syncthreads();
        const unsigned mask_hi = (shift == 24) ? 0u : (0xFFFFFFFFu << (shift + 8));
        for (int i = tid; i < NP; i += 1024) {
            unsigned v = __float_as_uint(row[i]);
            if ((v & mask_hi) == (prefix & mask_hi))
                atomicAdd(&whist[wid][(v >> shift) & 0xFFu], 1u);
        }
        __syncthreads();
        if (tid < 256) {
            unsigned t = 0;
            for (int w = 0; w < 16; ++w) t += whist[w][tid];
            chist[tid] = t;
        }
        __syncthreads();
        if (tid < 64) {
            const unsigned cA = chist[4 * lane + 0];
            const unsigned cB = chist[4 * lane + 1];
            const unsigned cC = chist[4 * lane + 2];
            const unsigned cD = chist[4 * lane + 3];
            const unsigned g = cA + cB + cC + cD;
            unsigned T = g;
            for (int d = 1; d < 64; d <<= 1) {
                unsigned t = __shfl_down(T, d, 64);
                if (lane + d < 64) T += t;
            }
            const unsigned E = T - g;
            const bool hit = (E < (unsigned)k) && ((unsigned)k <= T);
            unsigned long long msk = __ballot(hit);
            int wl = __ffsll(msk) - 1;
            if (lane == wl) {
                unsigned cum = E;
                int bsel = 4 * lane;
                int kn = k;
                const unsigned cc[4] = {cD, cC, cB, cA};
                for (int j = 0; j < 4; ++j) {
                    if (cum + cc[j] >= (unsigned)k) {
                        bsel = 4 * lane + 3 - j;
                        kn = k - (int)cum;
                        break;
                    }
                    cum += cc[j];
                }
                sh_bucket = bsel;
                sh_knew = kn;
            }
        }
        __syncthreads();
        prefix |= ((unsigned)sh_bucket) << shift;
        k = sh_knew;
        __syncthreads();
    }
    const float T = __uint_as_float(prefix);

    float msum = 0.f;
    int mcnt = 0;
    for (int i = tid; i < NP; i += 1024) {
        float v = row[i];
        if (__float_as_uint(v) > prefix) { msum += v; mcnt++; }
    }
    for (int s = 32; s > 0; s >>= 1) {
        msum += __shfl_down(msum, s, 64);
        mcnt += __shfl_down(mcnt, s, 64);
    }
    if (lane == 0) { wsum[wid] = msum; wcnt[wid] = mcnt; }
    __syncthreads();
    if (tid == 0) {
        float tot = 0.f;
        int cnt = 0;
        for (int w = 0; w < 16; ++w) { tot += wsum[w]; cnt += wcnt[w]; }
        atomicAdd(&accB[b * 2 + 1], tot + (float)(K0 - cnt) * T);
    }
}

// ---------------------------------------------------------------- final
__global__ void k_final(const int* __restrict__ npos,
                        const float* __restrict__ accB,
                        float* __restrict__ out) {
    if (threadIdx.x == 0 && blockIdx.x == 0) {
        int n = 0;
        float a0 = 0.f, a1 = 0.f;
        for (int b = 0; b < NB; ++b) {
            n += npos[b];
            a0 += accB[b * 2 + 0];
            a1 += accB[b * 2 + 1];
        }
        const float N = (float)n;
        out[0] = a0 / N;
        out[1] = a1 / N;
    }
}

extern "C" void kernel_launch(void* const* d_in, const int* in_sizes, int n_in,
                              void* d_out, int out_size, void* d_ws, size_t ws_size,
                              hipStream_t stream) {
    const float* pred   = (const float*)d_in[0];
    const float* tboxes = (const float*)d_in[1];
    const int*   tlabels = (const int*)d_in[2];
    const float* priors = (const float*)d_in[3];
    float* out = (float*)d_out;

    char* w = (char*)d_ws;
    float2* bt2 = (float2*)w;                       // 8*BPCNT bytes
    float*  lrk = (float*)(w + 8ull * BPCNT);       // 4*BPCNT bytes
    // mcand ALIASES lrk's space (397 KB < 3.16 MB): k_match writes it,
    // k_scatter reads it, THEN k_main overwrites the region as lrk.
    u64*    mcand = (u64*)(w + 8ull * BPCNT);
    int*    npos = (int*)(w + 12ull * BPCNT);       // NB i32
    float*  accB = (float*)(w + 12ull * BPCNT + 4ull * NB);  // NB*2 f32

    k_init<<<dim3(1), dim3(64), 0, stream>>>(npos, accB);
    k_match<<<dim3(MBLK, NB), dim3(256), 0, stream>>>(tboxes, priors, bt2, mcand);
    k_scatter<<<dim3(1), dim3(NB * NO), 0, stream>>>(mcand, bt2);
    k_main<<<dim3((NP + 63) / 64, NB), dim3(256), 0, stream>>>(
        pred, tboxes, tlabels, priors, bt2, lrk, npos, accB);
    k_select<<<dim3(NB), dim3(1024), 0, stream>>>(lrk, npos, accB);
    k_final<<<dim3(1), dim3(1), 0, stream>>>(npos, accB, out);
}